// Round 1
// 337.897 us; speedup vs baseline: 1.0302x; 1.0302x over previous
//
#include <hip/hip_runtime.h>
#include <hip/hip_bf16.h>
#include <stdint.h>

typedef __bf16 bf16;
typedef __bf16 bf16x2 __attribute__((ext_vector_type(2)));
typedef __bf16 bf16x4 __attribute__((ext_vector_type(4)));
typedef __bf16 bf16x8 __attribute__((ext_vector_type(8)));
typedef float f32x4 __attribute__((ext_vector_type(4)));

#define AS1 __attribute__((address_space(1)))
#define AS3 __attribute__((address_space(3)))

static __device__ __forceinline__ void async_cp16(const bf16* g, bf16* l) {
    __builtin_amdgcn_global_load_lds((const AS1 void*)g, (AS3 void*)l, 16, 0, 0);
}

static __device__ __forceinline__ bf16x4 cvt4(f32x4 v) {
    bf16x4 r;
    r[0] = (bf16)v[0]; r[1] = (bf16)v[1]; r[2] = (bf16)v[2]; r[3] = (bf16)v[3];
    return r;
}

static __device__ __forceinline__ float fast_exp2(float x) {
#if __has_builtin(__builtin_amdgcn_exp2f)
    return __builtin_amdgcn_exp2f(x);
#else
    return __expf(x * 0.69314718056f);
#endif
}

// ---------------------------------------------------------------------------
// fp32 -> bf16 bulk convert (grid-stride, float4)
__global__ __launch_bounds__(256) void cvt_kernel(
    const float* __restrict__ src, bf16* __restrict__ dst, int n4) {
    int i = blockIdx.x * 256 + threadIdx.x;
    const int stride = gridDim.x * 256;
    for (; i < n4; i += stride)
        ((bf16x4*)dst)[i] = cvt4(((const f32x4*)src)[i]);
}

// NOTE: epilogue is INLINED in both qkv kernels. Round 5 passed acc[4][4]
// into a helper; array-decay defeated SROA -> acc lived in scratch -> every
// MFMA accumulate became a global-memory RMW. Do not refactor accumulators
// through pointers.
//
// Q is pre-scaled by C2 = 0.125*log2(e) here so flash_attn's QK MFMA output
// is already in the exp2 domain (the rel-pos tables compensate with *8).

#define QKV_EPILOGUE()                                                        \
    for (int nt = 0; nt < 4; nt++) {                                          \
        const int n_ = n0 + wn + nt * 16 + lm;                                \
        const float bv = bias[n_];                                            \
        const int s = n_ >> 10, rem = n_ & 1023;                              \
        const int h = rem >> 6, d = rem & 63;                                 \
        const float qsc = (s == 0) ? 0.18033688011112042f : 1.0f;             \
        for (int mt = 0; mt < 4; mt++) {                                      \
            for (int r = 0; r < 4; r++) {                                     \
                const int m_ = m0 + wm + mt * 16 + quad * 4 + r;              \
                const int b = m_ / 1568;                                      \
                const int pix = m_ - b * 1568;                                \
                const int g = b * 16 + h;                                     \
                const bf16 v = (bf16)((acc[mt][nt][r] + bv) * qsc);           \
                if (s == 0)      Qb[((size_t)g * 1568 + pix) * 64 + d] = v;   \
                else if (s == 1) Kb[((size_t)g * 1568 + pix) * 64 + d] = v;   \
                else {                                                        \
                    const int lk = pix & 31;                                  \
                    const int ppix = (pix & ~31) | ((lk & 15) << 1) | (lk >> 4); \
                    Vt[((size_t)g * 64 + d) * 1568 + ppix] = v;               \
                }                                                             \
            }                                                                 \
        }                                                                     \
    }

// ---------------------------------------------------------------------------
// Kernel 1a: QKV projection, bf16 inputs (pre-converted), m97 async staging.
__global__ __launch_bounds__(256) void qkv_gemm_bf16(
    const bf16* __restrict__ A, const bf16* __restrict__ W,
    const float* __restrict__ bias, bf16* __restrict__ Qb,
    bf16* __restrict__ Kb, bf16* __restrict__ Vt) {
    __shared__ bf16 As[128 * 32];
    __shared__ bf16 Bs[128 * 32];
    const int t = threadIdx.x;
    const int wid = t >> 6, lane = t & 63;
    const int m0 = blockIdx.x * 128, n0 = blockIdx.y * 128;
    const int wm = (wid & 1) * 64, wn = (wid >> 1) * 64;
    const int r_i = lane >> 2, c8 = (lane & 3) * 8;
    const int lm = lane & 15, quad = lane >> 4;

    f32x4 acc[4][4] = {};
    for (int k0 = 0; k0 < 1024; k0 += 32) {
        __syncthreads();
        for (int i = 0; i < 2; i++) {
            const int blk = wid * 2 + i;
            async_cp16(A + (size_t)(m0 + blk * 16 + r_i) * 1024 + k0 + c8, As + blk * 512);
            async_cp16(W + (size_t)(n0 + blk * 16 + r_i) * 1024 + k0 + c8, Bs + blk * 512);
        }
        __syncthreads();
        bf16x8 af[4], bfr[4];
        for (int x = 0; x < 4; x++) {
            af[x]  = *(const bf16x8*)&As[(wm + x * 16 + lm) * 32 + quad * 8];
            bfr[x] = *(const bf16x8*)&Bs[(wn + x * 16 + lm) * 32 + quad * 8];
        }
        for (int mt = 0; mt < 4; mt++)
            for (int nt = 0; nt < 4; nt++)
                acc[mt][nt] = __builtin_amdgcn_mfma_f32_16x16x32_bf16(af[mt], bfr[nt], acc[mt][nt], 0, 0, 0);
    }
    QKV_EPILOGUE()
}

// Kernel 1b: fallback — fp32 inputs, convert at LDS-stage time.
__global__ __launch_bounds__(256) void qkv_gemm_f32(
    const float* __restrict__ A, const float* __restrict__ W,
    const float* __restrict__ bias, bf16* __restrict__ Qb,
    bf16* __restrict__ Kb, bf16* __restrict__ Vt) {
    __shared__ bf16 As[128 * 32];
    __shared__ bf16 Bs[128 * 32];
    const int t = threadIdx.x;
    const int wid = t >> 6, lane = t & 63;
    const int m0 = blockIdx.x * 128, n0 = blockIdx.y * 128;
    const int wm = (wid & 1) * 64, wn = (wid >> 1) * 64;
    const int lm = lane & 15, quad = lane >> 4;

    f32x4 acc[4][4] = {};
    for (int k0 = 0; k0 < 1024; k0 += 32) {
        __syncthreads();
        for (int i = 0; i < 4; i++) {
            const int idx = t + i * 256;
            const int row = idx >> 3, c4 = (idx & 7) * 4;
            const f32x4 av = *(const f32x4*)&A[(size_t)(m0 + row) * 1024 + k0 + c4];
            const f32x4 wv = *(const f32x4*)&W[(size_t)(n0 + row) * 1024 + k0 + c4];
            *(bf16x4*)&As[row * 32 + c4] = cvt4(av);
            *(bf16x4*)&Bs[row * 32 + c4] = cvt4(wv);
        }
        __syncthreads();
        bf16x8 af[4], bfr[4];
        for (int x = 0; x < 4; x++) {
            af[x]  = *(const bf16x8*)&As[(wm + x * 16 + lm) * 32 + quad * 8];
            bfr[x] = *(const bf16x8*)&Bs[(wn + x * 16 + lm) * 32 + quad * 8];
        }
        for (int mt = 0; mt < 4; mt++)
            for (int nt = 0; nt < 4; nt++)
                acc[mt][nt] = __builtin_amdgcn_mfma_f32_16x16x32_bf16(af[mt], bfr[nt], acc[mt][nt], 0, 0, 0);
    }
    QKV_EPILOGUE()
}

// ---------------------------------------------------------------------------
// Kernel 2: flash attention, KVBLK=64, 25 tiles.
//  - Rel-pos tables are f32, log2-domain, block-compressed (hq spans <=4 values
//    per block so Th needs only 59 cols), with -SHIFT*log2e folded into Th and
//    the 0.125*log2e scale folded into Q (qkv epilogue). Softmax is then
//    p = exp2(mfma_out) with zero per-element VALU beyond the exp itself.
//  - K/V LDS tiles are [64][64] bf16 with XOR swizzle (byte ^= (row&7)<<4):
//    b128 reads hit all 8 16B granules instead of serializing on one column.
//  - l is accumulated by an extra MFMA with an all-ones B operand (matrix pipe
//    is idle); removes the per-element adds and the final shuffle reduction.
//  - Last tile: keys 1568..1599 are invalid; their C-input is set to -3e4
//    (p underflows to exact 0) under a wave-uniform branch; prefetch rows/cols
//    are clamped in-bounds so staged garbage is finite (0 * finite = 0).
__global__ __launch_bounds__(256) void flash_attn(
    const bf16* __restrict__ Qb, const bf16* __restrict__ Kb,
    const bf16* __restrict__ Vt, const float* __restrict__ rph,
    const float* __restrict__ rpw, bf16* __restrict__ AO) {
    const int x = blockIdx.x;
    const int xcd = x & 7, j = x >> 3;          // j in 0..199
    const int g = xcd * 8 + j / 25;
    const int qblk = j - (j / 25) * 25;
    const int q0 = qblk * 64;
    const int hqb = q0 / 28;                    // first image row of this block

    // LDS 51712 B -> 3 blocks/CU.
    // region A: Th [64][60] f32 (15360) + Tw [64][58] f32 (14848), live whole kernel
    // region B (21504): prologue {Qs[64][72] | RPs[64][72]} ; loop {Ks,Vs,Ps}
    __shared__ __align__(16) char smem[51712];
    float* Th = (float*)smem;
    float* Tw = (float*)(smem + 15360);
    const char* ThC = (const char*)smem;
    const char* TwC = (const char*)(smem + 15360);
    char* B   = smem + 30208;
    bf16* Qs  = (bf16*)B;                       // [64][72] prologue phase 0
    bf16* RPs = (bf16*)B;                       // [64][72] prologue phases 1-2
    char* KsC = B;                              // [64][128B] swizzled, loop
    char* VsC = B + 8192;                       // [64][128B] swizzled, loop
    bf16* Ps  = (bf16*)(B + 16384);             // [4][16][40] loop (permuted keys)

    const int t = threadIdx.x, wid = t >> 6, lane = t & 63;
    const int lm = lane & 15, quad = lane >> 4;
    const int qbase_l = wid * 16 + quad * 4;
    const int swz = (lm & 7) << 4;

    // phase 0: stage Q tile [64][64] -> LDS (rows clamped for the q tail)
    for (int c = t; c < 512; c += 256) {
        const int row = c >> 3, col = (c & 7) * 8;
        const int qg = min(q0 + row, 1567);
        *(bf16x8*)&Qs[row * 72 + col] =
            *(const bf16x8*)&Qb[((size_t)g * 1568 + qg) * 64 + col];
    }
    __syncthreads();
    const int qrow_l = wid * 16 + lm;
    const bf16x8 qf0 = *(const bf16x8*)&Qs[qrow_l * 72 + quad * 8];
    const bf16x8 qf1 = *(const bf16x8*)&Qs[qrow_l * 72 + 32 + quad * 8];

    // per-lane T-gather byte-address bases (loop subtracts hk*4 / wk*4)
    int thbB[4], twbB[4];
#pragma unroll
    for (int r = 0; r < 4; r++) {
        const int qg = min(q0 + qbase_l + r, 1567);
        const int hq = qg / 28, wq = qg - hq * 28;
        thbB[r] = ((qbase_l + r) * 60 + (hq - hqb) + 55) * 4;
        twbB[r] = ((qbase_l + r) * 58 + wq + 27) * 4;
    }

    // initial K/V register prefetch for tile 0 (overlaps the prologue MFMAs)
    bf16x8 kreg[2], vreg[2];
#pragma unroll
    for (int i = 0; i < 2; i++) {
        const int idx = (i << 8) + t;
        kreg[i] = *(const bf16x8*)&Kb[((size_t)g * 1568 + (idx >> 3)) * 64 + ((idx & 7) << 3)];
        vreg[i] = *(const bf16x8*)&Vt[((size_t)g * 64 + (idx >> 3)) * 1568 + ((idx & 7) << 3)];
    }
    __syncthreads();  // all Qs reads done before RPs overwrites

    // phase 1: stage rph rows hqb..hqb+63 (clamped; only c<59 read), Th MFMA
    for (int c = t; c < 1024; c += 256) {
        const int row = c >> 4, col = (c & 15) * 4;
        const int rg = min(hqb + row, 110);
        *(bf16x4*)&RPs[row * 72 + col] = cvt4(*(const f32x4*)&rph[rg * 64 + col]);
    }
    __syncthreads();
    f32x4 acch[4];
#pragma unroll
    for (int nt = 0; nt < 4; nt++) {
        const bf16x8 b0 = *(const bf16x8*)&RPs[(nt * 16 + lm) * 72 + quad * 8];
        const bf16x8 b1 = *(const bf16x8*)&RPs[(nt * 16 + lm) * 72 + 32 + quad * 8];
        f32x4 a = {};
        a = __builtin_amdgcn_mfma_f32_16x16x32_bf16(qf0, b0, a, 0, 0, 0);
        a = __builtin_amdgcn_mfma_f32_16x16x32_bf16(qf1, b1, a, 0, 0, 0);
        acch[nt] = a;
    }
    __syncthreads();  // all RPh reads done before RPw overwrites

    // phase 2: stage rpw, write Th (f32, *8, -S2 folded), Tw MFMA + write (*8)
    for (int c = t; c < 1024; c += 256) {
        const int row = c >> 4, col = (c & 15) * 4;
        const int rg = min(row, 54);
        *(bf16x4*)&RPs[row * 72 + col] = cvt4(*(const f32x4*)&rpw[rg * 64 + col]);
    }
#pragma unroll
    for (int nt = 0; nt < 4; nt++) {
        const int c = nt * 16 + lm;
        if (c < 59) {
#pragma unroll
            for (int r = 0; r < 4; r++)
                Th[(qbase_l + r) * 60 + c] = acch[nt][r] * 8.0f - 14.4269504f;
        }
    }
    __syncthreads();
#pragma unroll
    for (int nt = 0; nt < 4; nt++) {
        const bf16x8 b0 = *(const bf16x8*)&RPs[(nt * 16 + lm) * 72 + quad * 8];
        const bf16x8 b1 = *(const bf16x8*)&RPs[(nt * 16 + lm) * 72 + 32 + quad * 8];
        f32x4 a = {};
        a = __builtin_amdgcn_mfma_f32_16x16x32_bf16(qf0, b0, a, 0, 0, 0);
        a = __builtin_amdgcn_mfma_f32_16x16x32_bf16(qf1, b1, a, 0, 0, 0);
        const int c = nt * 16 + lm;
        if (c < 55) {
#pragma unroll
            for (int r = 0; r < 4; r++)
                Tw[(qbase_l + r) * 58 + c] = a[r] * 8.0f;
        }
    }
    // loop's first __syncthreads covers: RPw reads + T writes vs Ks staging.
    // T-gather in the loop only reads this wave's OWN rows -> no extra barrier.

    f32x4 o[4] = {};
    f32x4 lsum = {};
    bf16x8 ones;
#pragma unroll
    for (int i = 0; i < 8; i++) ones[i] = (bf16)1.0f;

    // per-fragment hk/wk byte offsets for keys f*16+lm; advance by 64 per tile
    int hkB[4], wkB[4];
#pragma unroll
    for (int f = 0; f < 4; f++) {
        const int k = f * 16 + lm;
        const int hk = k / 28;
        hkB[f] = hk * 4;
        wkB[f] = (k - hk * 28) * 4;
    }
    bf16* Pw = &Ps[wid * 640];

    for (int kt = 0; kt < 25; kt++) {
        // rel-pos bias as the QK MFMA C-input (own-wave T rows; overlaps prev PV)
        f32x4 s[4];
#pragma unroll
        for (int f = 0; f < 2; f++)
#pragma unroll
            for (int r = 0; r < 4; r++)
                s[f][r] = *(const float*)(ThC + (thbB[r] - hkB[f]))
                        + *(const float*)(TwC + (twbB[r] - wkB[f]));
        if (kt < 24) {
#pragma unroll
            for (int f = 2; f < 4; f++)
#pragma unroll
                for (int r = 0; r < 4; r++)
                    s[f][r] = *(const float*)(ThC + (thbB[r] - hkB[f]))
                            + *(const float*)(TwC + (twbB[r] - wkB[f]));
        } else {
#pragma unroll
            for (int f = 2; f < 4; f++)
#pragma unroll
                for (int r = 0; r < 4; r++)
                    s[f][r] = -30000.0f;         // keys >= 1568: p == 0
        }

        __syncthreads();                         // prev tile's readers done
        // stage K/V (swizzled) from regs
#pragma unroll
        for (int i = 0; i < 2; i++) {
            const int idx = (i << 8) + t;
            const int row = idx >> 3;
            const int cb = (((idx & 7) << 4) ^ ((row & 7) << 4));
            *(bf16x8*)(KsC + row * 128 + cb) = kreg[i];
            *(bf16x8*)(VsC + row * 128 + cb) = vreg[i];
        }
        // prefetch next tile (addresses clamped in-bounds; garbage is masked)
        {
            const int kb = min(kt + 1, 24) << 6;
#pragma unroll
            for (int i = 0; i < 2; i++) {
                const int idx = (i << 8) + t;
                const int krow = min(kb + (idx >> 3), 1567);
                kreg[i] = *(const bf16x8*)&Kb[((size_t)g * 1568 + krow) * 64 + ((idx & 7) << 3)];
                const int vcol = min(kb + ((idx & 7) << 3), 1560);
                vreg[i] = *(const bf16x8*)&Vt[((size_t)g * 64 + (idx >> 3)) * 1568 + vcol];
            }
        }
        __syncthreads();

        // S = QK^T + bias  (4 key-fragments x K=64)
        __builtin_amdgcn_s_setprio(1);
#pragma unroll
        for (int f = 0; f < 4; f++) {
            const char* rp = KsC + (f * 16 + lm) * 128;
            const int x0 = (quad * 16) ^ swz;
            const bf16x8 ka = *(const bf16x8*)(rp + x0);
            const bf16x8 kb2 = *(const bf16x8*)(rp + (x0 ^ 64));
            s[f] = __builtin_amdgcn_mfma_f32_16x16x32_bf16(qf0, ka, s[f], 0, 0, 0);
            s[f] = __builtin_amdgcn_mfma_f32_16x16x32_bf16(qf1, kb2, s[f], 0, 0, 0);
        }
        __builtin_amdgcn_s_setprio(0);

        // advance keys by 64 = 2*28 + 8 (byte-scaled: wk*4, hk*4)
#pragma unroll
        for (int f = 0; f < 4; f++) {
            wkB[f] += 32; hkB[f] += 8;
            if (wkB[f] >= 112) { wkB[f] -= 112; hkB[f] += 4; }
        }

        // two 32-key PV halves; P buffer reused (same-wave in-order DS)
#pragma unroll
        for (int h = 0; h < 2; h++) {
#pragma unroll
            for (int r = 0; r < 4; r++) {
                const float p0 = fast_exp2(s[2 * h][r]);
                const float p1 = fast_exp2(s[2 * h + 1][r]);
                bf16x2 pp; pp[0] = (bf16)p0; pp[1] = (bf16)p1;
                *(bf16x2*)&Pw[(quad * 4 + r) * 40 + lm * 2] = pp;
            }
            __asm__ volatile("s_waitcnt lgkmcnt(0)" ::: "memory");
            const bf16x8 pf = *(const bf16x8*)&Pw[lm * 40 + quad * 8];
            lsum = __builtin_amdgcn_mfma_f32_16x16x32_bf16(pf, ones, lsum, 0, 0, 0);
            __builtin_amdgcn_s_setprio(1);
#pragma unroll
            for (int dt = 0; dt < 4; dt++) {
                const bf16x8 vf = *(const bf16x8*)(VsC + (dt * 16 + lm) * 128 +
                                                   (((h << 6) + quad * 16) ^ swz));
                o[dt] = __builtin_amdgcn_mfma_f32_16x16x32_bf16(pf, vf, o[dt], 0, 0, 0);
            }
            __builtin_amdgcn_s_setprio(0);
        }
    }

    // epilogue: lsum already holds per-row softmax denominators (no shuffle)
    if (q0 + wid * 16 < 1568) {
        const int bo = g >> 4, hh = g & 15;
#pragma unroll
        for (int r = 0; r < 4; r++) {
            const float inv = 1.0f / lsum[r];
            const size_t base = ((size_t)bo * 1568 + q0 + qbase_l + r) * 1024 + hh * 64;
#pragma unroll
            for (int dt = 0; dt < 4; dt++)
                AO[base + dt * 16 + lm] = (bf16)(o[dt][r] * inv);
        }
    }
}

// ---------------------------------------------------------------------------
// Kernel 3a: output projection, both operands bf16 (W pre-converted).
__global__ __launch_bounds__(256) void proj_gemm_bf16(
    const bf16* __restrict__ A, const bf16* __restrict__ W,
    const float* __restrict__ bias, float* __restrict__ out) {
    __shared__ bf16 As[128 * 32];
    __shared__ bf16 Bs[128 * 32];
    const int t = threadIdx.x;
    const int wid = t >> 6, lane = t & 63;
    const int m0 = blockIdx.x * 128, n0 = blockIdx.y * 128;
    const int wm = (wid & 1) * 64, wn = (wid >> 1) * 64;
    const int r_i = lane >> 2, c8 = (lane & 3) * 8;
    const int lm = lane & 15, quad = lane >> 4;

    f32x4 acc[4][4] = {};
    for (int k0 = 0; k0 < 1024; k0 += 32) {
        __syncthreads();
        for (int i = 0; i < 2; i++) {
            const int blk = wid * 2 + i;
            async_cp16(A + (size_t)(m0 + blk * 16 + r_i) * 1024 + k0 + c8, As + blk * 512);
            async_cp16(W + (size_t)(n0 + blk * 16 + r_i) * 1024 + k0 + c8, Bs + blk * 512);
        }
        __syncthreads();
        bf16x8 af[4], bfr[4];
        for (int x = 0; x < 4; x++) {
            af[x]  = *(const bf16x8*)&As[(wm + x * 16 + lm) * 32 + quad * 8];
            bfr[x] = *(const bf16x8*)&Bs[(wn + x * 16 + lm) * 32 + quad * 8];
        }
        for (int mt = 0; mt < 4; mt++)
            for (int nt = 0; nt < 4; nt++)
                acc[mt][nt] = __builtin_amdgcn_mfma_f32_16x16x32_bf16(af[mt], bfr[nt], acc[mt][nt], 0, 0, 0);
    }
    for (int nt = 0; nt < 4; nt++) {
        const int n_ = n0 + wn + nt * 16 + lm;
        const float bv = bias[n_];
        for (int mt = 0; mt < 4; mt++)
            for (int r = 0; r < 4; r++) {
                const int m_ = m0 + wm + mt * 16 + quad * 4 + r;
                out[(size_t)m_ * 1024 + n_] = acc[mt][nt][r] + bv;
            }
    }
}

// Kernel 3b: fallback — W fp32, converted at stage time.
__global__ __launch_bounds__(256) void proj_gemm_f32(
    const bf16* __restrict__ A, const float* __restrict__ W,
    const float* __restrict__ bias, float* __restrict__ out) {
    __shared__ bf16 As[128 * 32];
    __shared__ bf16 Bs[128 * 32];
    const int t = threadIdx.x;
    const int wid = t >> 6, lane = t & 63;
    const int m0 = blockIdx.x * 128, n0 = blockIdx.y * 128;
    const int wm = (wid & 1) * 64, wn = (wid >> 1) * 64;
    const int r_i = lane >> 2, c8 = (lane & 3) * 8;
    const int lm = lane & 15, quad = lane >> 4;

    f32x4 acc[4][4] = {};
    for (int k0 = 0; k0 < 1024; k0 += 32) {
        __syncthreads();
        for (int i = 0; i < 2; i++) {
            const int blk = wid * 2 + i;
            async_cp16(A + (size_t)(m0 + blk * 16 + r_i) * 1024 + k0 + c8, As + blk * 512);
        }
        for (int i = 0; i < 4; i++) {
            const int idx = t + i * 256;
            const int row = idx >> 3, c4 = (idx & 7) * 4;
            const f32x4 wv = *(const f32x4*)&W[(size_t)(n0 + row) * 1024 + k0 + c4];
            *(bf16x4*)&Bs[row * 32 + c4] = cvt4(wv);
        }
        __syncthreads();
        bf16x8 af[4], bfr[4];
        for (int x = 0; x < 4; x++) {
            af[x]  = *(const bf16x8*)&As[(wm + x * 16 + lm) * 32 + quad * 8];
            bfr[x] = *(const bf16x8*)&Bs[(wn + x * 16 + lm) * 32 + quad * 8];
        }
        for (int mt = 0; mt < 4; mt++)
            for (int nt = 0; nt < 4; nt++)
                acc[mt][nt] = __builtin_amdgcn_mfma_f32_16x16x32_bf16(af[mt], bfr[nt], acc[mt][nt], 0, 0, 0);
    }
    for (int nt = 0; nt < 4; nt++) {
        const int n_ = n0 + wn + nt * 16 + lm;
        const float bv = bias[n_];
        for (int mt = 0; mt < 4; mt++)
            for (int r = 0; r < 4; r++) {
                const int m_ = m0 + wm + mt * 16 + quad * 4 + r;
                out[(size_t)m_ * 1024 + n_] = acc[mt][nt][r] + bv;
            }
    }
}

// ---------------------------------------------------------------------------
extern "C" void kernel_launch(void* const* d_in, const int* in_sizes, int n_in,
                              void* d_out, int out_size, void* d_ws, size_t ws_size,
                              hipStream_t stream) {
    const float* hs     = (const float*)d_in[0];
    const float* qkv_w  = (const float*)d_in[1];
    const float* qkv_b  = (const float*)d_in[2];
    const float* proj_w = (const float*)d_in[3];
    const float* proj_b = (const float*)d_in[4];
    const float* rph    = (const float*)d_in[5];
    const float* rpw    = (const float*)d_in[6];
    float* out = (float*)d_out;

    const size_t GQ = (size_t)64 * 1568 * 64;  // elems per Q/K/V
    const size_t N_HS = (size_t)6272 * 1024;
    const size_t N_QW = (size_t)3072 * 1024;
    const size_t N_PW = (size_t)1024 * 1024;
    bf16* Qb = (bf16*)d_ws;                    // [g][pix][64] (pre-scaled by C2)
    bf16* Kb = Qb + GQ;                        // [g][pix][64]
    bf16* Vt = Kb + GQ;                        // [g][d][ppix] (permuted keys)
    bf16* AO = Vt + GQ;                        // [6272][1024]
    bf16* hs_bf    = AO + GQ;
    bf16* qkvw_bf  = hs_bf + N_HS;
    bf16* projw_bf = qkvw_bf + N_QW;
    const size_t need = (4 * GQ + N_HS + N_QW + N_PW) * sizeof(bf16); // 72.6 MB

    if (ws_size >= need) {
        cvt_kernel<<<512, 256, 0, stream>>>(hs, hs_bf, (int)(N_HS / 4));
        cvt_kernel<<<512, 256, 0, stream>>>(qkv_w, qkvw_bf, (int)(N_QW / 4));
        cvt_kernel<<<256, 256, 0, stream>>>(proj_w, projw_bf, (int)(N_PW / 4));
        qkv_gemm_bf16<<<dim3(49, 24), 256, 0, stream>>>(hs_bf, qkvw_bf, qkv_b, Qb, Kb, Vt);
        flash_attn<<<1600, 256, 0, stream>>>(Qb, Kb, Vt, rph, rpw, AO);
        proj_gemm_bf16<<<dim3(49, 8), 256, 0, stream>>>(AO, projw_bf, proj_b, out);
    } else {
        qkv_gemm_f32<<<dim3(49, 24), 256, 0, stream>>>(hs, qkv_w, qkv_b, Qb, Kb, Vt);
        flash_attn<<<1600, 256, 0, stream>>>(Qb, Kb, Vt, rph, rpw, AO);
        proj_gemm_f32<<<dim3(49, 8), 256, 0, stream>>>(AO, proj_w, proj_b, out);
    }
}

// Round 2
// 328.306 us; speedup vs baseline: 1.0602x; 1.0292x over previous
//
#include <hip/hip_runtime.h>
#include <hip/hip_bf16.h>
#include <stdint.h>

typedef __bf16 bf16;
typedef __bf16 bf16x2 __attribute__((ext_vector_type(2)));
typedef __bf16 bf16x4 __attribute__((ext_vector_type(4)));
typedef __bf16 bf16x8 __attribute__((ext_vector_type(8)));
typedef float f32x4 __attribute__((ext_vector_type(4)));

#define AS1 __attribute__((address_space(1)))
#define AS3 __attribute__((address_space(3)))

static __device__ __forceinline__ void async_cp16(const bf16* g, bf16* l) {
    __builtin_amdgcn_global_load_lds((const AS1 void*)g, (AS3 void*)l, 16, 0, 0);
}

static __device__ __forceinline__ bf16x4 cvt4(f32x4 v) {
    bf16x4 r;
    r[0] = (bf16)v[0]; r[1] = (bf16)v[1]; r[2] = (bf16)v[2]; r[3] = (bf16)v[3];
    return r;
}

static __device__ __forceinline__ float fast_exp2(float x) {
#if __has_builtin(__builtin_amdgcn_exp2f)
    return __builtin_amdgcn_exp2f(x);
#else
    return __expf(x * 0.69314718056f);
#endif
}

// ---------------------------------------------------------------------------
// fp32 -> bf16 bulk convert (grid-stride, float4)
__global__ __launch_bounds__(256) void cvt_kernel(
    const float* __restrict__ src, bf16* __restrict__ dst, int n4) {
    int i = blockIdx.x * 256 + threadIdx.x;
    const int stride = gridDim.x * 256;
    for (; i < n4; i += stride)
        ((bf16x4*)dst)[i] = cvt4(((const f32x4*)src)[i]);
}

// ---------------------------------------------------------------------------
// Kone: global one-hot table [1600 keys][32 dims] bf16 (102 KB, L2-resident).
// dim j in 0..27  : 1 iff j == 27 - wk(key)            (wk = key % 28)
// dim 28+jj       : 1 iff jj == 3 - (hk(key) - ha(kt)) (hk = key/28, ha = tile base row)
// Contracting Q'[q][j] (see flash prologue) against this reproduces
// Th_q[(hq-hqb)+55-hk] + Tw_q[wq+27-wk], i.e. the decomposed rel-pos bias.
__global__ __launch_bounds__(256) void build_kone(bf16* __restrict__ Kone) {
    const int idx = blockIdx.x * 256 + threadIdx.x;   // 6400 = 1600 keys * 4 chunks
    if (idx >= 6400) return;
    const int key = idx >> 2, chunk = idx & 3;
    const int hk = key / 28;
    const int wk = key - hk * 28;
    const int kt = key >> 6;
    const int ha = (kt << 6) / 28;
    const int jw = 27 - wk;
    const int jh = 31 - (hk - ha);
    bf16x8 v;
#pragma unroll
    for (int e = 0; e < 8; e++) {
        const int j = chunk * 8 + e;
        v[e] = (j == jw || j == jh) ? (bf16)1.0f : (bf16)0.0f;
    }
    *(bf16x8*)&Kone[key * 32 + chunk * 8] = v;
}

// NOTE: epilogue is INLINED in both qkv kernels. Round 5 passed acc[4][4]
// into a helper; array-decay defeated SROA -> acc lived in scratch -> every
// MFMA accumulate became a global-memory RMW. Do not refactor accumulators
// through pointers.
//
// Q is pre-scaled by C2 = 0.125*log2(e) here so flash_attn's QK MFMA output
// is already in the exp2 domain (the rel-pos tables compensate with *8).

#define QKV_EPILOGUE()                                                        \
    for (int nt = 0; nt < 4; nt++) {                                          \
        const int n_ = n0 + wn + nt * 16 + lm;                                \
        const float bv = bias[n_];                                            \
        const int s = n_ >> 10, rem = n_ & 1023;                              \
        const int h = rem >> 6, d = rem & 63;                                 \
        const float qsc = (s == 0) ? 0.18033688011112042f : 1.0f;             \
        for (int mt = 0; mt < 4; mt++) {                                      \
            for (int r = 0; r < 4; r++) {                                     \
                const int m_ = m0 + wm + mt * 16 + quad * 4 + r;              \
                const int b = m_ / 1568;                                      \
                const int pix = m_ - b * 1568;                                \
                const int g = b * 16 + h;                                     \
                const bf16 v = (bf16)((acc[mt][nt][r] + bv) * qsc);           \
                if (s == 0)      Qb[((size_t)g * 1568 + pix) * 64 + d] = v;   \
                else if (s == 1) Kb[((size_t)g * 1568 + pix) * 64 + d] = v;   \
                else {                                                        \
                    const int lk = pix & 31;                                  \
                    const int ppix = (pix & ~31) | ((lk & 15) << 1) | (lk >> 4); \
                    Vt[((size_t)g * 64 + d) * 1568 + ppix] = v;               \
                }                                                             \
            }                                                                 \
        }                                                                     \
    }

// ---------------------------------------------------------------------------
// Kernel 1a: QKV projection, bf16 inputs (pre-converted), m97 async staging.
__global__ __launch_bounds__(256) void qkv_gemm_bf16(
    const bf16* __restrict__ A, const bf16* __restrict__ W,
    const float* __restrict__ bias, bf16* __restrict__ Qb,
    bf16* __restrict__ Kb, bf16* __restrict__ Vt) {
    __shared__ bf16 As[128 * 32];
    __shared__ bf16 Bs[128 * 32];
    const int t = threadIdx.x;
    const int wid = t >> 6, lane = t & 63;
    const int m0 = blockIdx.x * 128, n0 = blockIdx.y * 128;
    const int wm = (wid & 1) * 64, wn = (wid >> 1) * 64;
    const int r_i = lane >> 2, c8 = (lane & 3) * 8;
    const int lm = lane & 15, quad = lane >> 4;

    f32x4 acc[4][4] = {};
    for (int k0 = 0; k0 < 1024; k0 += 32) {
        __syncthreads();
        for (int i = 0; i < 2; i++) {
            const int blk = wid * 2 + i;
            async_cp16(A + (size_t)(m0 + blk * 16 + r_i) * 1024 + k0 + c8, As + blk * 512);
            async_cp16(W + (size_t)(n0 + blk * 16 + r_i) * 1024 + k0 + c8, Bs + blk * 512);
        }
        __syncthreads();
        bf16x8 af[4], bfr[4];
        for (int x = 0; x < 4; x++) {
            af[x]  = *(const bf16x8*)&As[(wm + x * 16 + lm) * 32 + quad * 8];
            bfr[x] = *(const bf16x8*)&Bs[(wn + x * 16 + lm) * 32 + quad * 8];
        }
        for (int mt = 0; mt < 4; mt++)
            for (int nt = 0; nt < 4; nt++)
                acc[mt][nt] = __builtin_amdgcn_mfma_f32_16x16x32_bf16(af[mt], bfr[nt], acc[mt][nt], 0, 0, 0);
    }
    QKV_EPILOGUE()
}

// Kernel 1b: fallback — fp32 inputs, convert at LDS-stage time.
__global__ __launch_bounds__(256) void qkv_gemm_f32(
    const float* __restrict__ A, const float* __restrict__ W,
    const float* __restrict__ bias, bf16* __restrict__ Qb,
    bf16* __restrict__ Kb, bf16* __restrict__ Vt) {
    __shared__ bf16 As[128 * 32];
    __shared__ bf16 Bs[128 * 32];
    const int t = threadIdx.x;
    const int wid = t >> 6, lane = t & 63;
    const int m0 = blockIdx.x * 128, n0 = blockIdx.y * 128;
    const int wm = (wid & 1) * 64, wn = (wid >> 1) * 64;
    const int lm = lane & 15, quad = lane >> 4;

    f32x4 acc[4][4] = {};
    for (int k0 = 0; k0 < 1024; k0 += 32) {
        __syncthreads();
        for (int i = 0; i < 4; i++) {
            const int idx = t + i * 256;
            const int row = idx >> 3, c4 = (idx & 7) * 4;
            const f32x4 av = *(const f32x4*)&A[(size_t)(m0 + row) * 1024 + k0 + c4];
            const f32x4 wv = *(const f32x4*)&W[(size_t)(n0 + row) * 1024 + k0 + c4];
            *(bf16x4*)&As[row * 32 + c4] = cvt4(av);
            *(bf16x4*)&Bs[row * 32 + c4] = cvt4(wv);
        }
        __syncthreads();
        bf16x8 af[4], bfr[4];
        for (int x = 0; x < 4; x++) {
            af[x]  = *(const bf16x8*)&As[(wm + x * 16 + lm) * 32 + quad * 8];
            bfr[x] = *(const bf16x8*)&Bs[(wn + x * 16 + lm) * 32 + quad * 8];
        }
        for (int mt = 0; mt < 4; mt++)
            for (int nt = 0; nt < 4; nt++)
                acc[mt][nt] = __builtin_amdgcn_mfma_f32_16x16x32_bf16(af[mt], bfr[nt], acc[mt][nt], 0, 0, 0);
    }
    QKV_EPILOGUE()
}

// ---------------------------------------------------------------------------
// Kernel 2: flash attention, KVBLK=64, 25 tiles.
//  - The ENTIRE rel-pos bias rides inside the QK MFMA as a one-hot augmented
//    K=32 block: Q' = [TwS window | Th window], Kone = global one-hot (above).
//    No per-key table gathers, no f32 adds, no key-advance bookkeeping.
//  - No softmax shift: p = exp2(s) directly; the uniform 2^shift factor
//    cancels exactly in o/l. s stays small (~|6|), f32/bf16 safe.
//  - K/V LDS tiles are [64][64] bf16 with XOR swizzle (byte ^= (row&7)<<4).
//  - l accumulated by MFMA against an all-ones B operand.
//  - Last tile: fragments f=2,3 (keys 1568..1599) overwritten with -3e4
//    before exp2; prefetch addresses clamped in-bounds (finite garbage only).
__global__ __launch_bounds__(256) void flash_attn(
    const bf16* __restrict__ Qb, const bf16* __restrict__ Kb,
    const bf16* __restrict__ Vt, const float* __restrict__ rph,
    const float* __restrict__ rpw, const bf16* __restrict__ Kone,
    bf16* __restrict__ AO) {
    const int x = blockIdx.x;
    const int xcd = x & 7, j = x >> 3;          // j in 0..199
    const int g = xcd * 8 + j / 25;
    const int qblk = j - (j / 25) * 25;
    const int q0 = qblk * 64;
    const int hqb = q0 / 28;                    // first image row of this block

    // LDS 45312 B -> 3 blocks/CU.
    // region A (19712): Th [64][61] f32 (15616, col-shifted +2) + TwS [64][32] bf16 (4096)
    // region B (25600): prologue {Qs[64][72] | RPs[64][72] + TwF[64][58] f32}
    //                   loop {Ks 8192, Vs 8192, KoneS 4096, Ps 5120}
    __shared__ __align__(16) char smem[45312];
    float* Th  = (float*)smem;                  // [64][61] f32, cols shifted +2
    const char* ThC = (const char*)smem;
    bf16* TwS = (bf16*)(smem + 15616);          // [64][32] bf16 fragment table
    char* B   = smem + 19712;
    bf16* Qs  = (bf16*)B;                       // [64][72]  prologue phase 0
    bf16* RPs = (bf16*)B;                       // [64][72]  prologue phases 1-2
    float* TwF = (float*)(B + 9216);            // [64][58] f32 scratch (phase 2)
    char* KsC = B;                              // [64][128B] swizzled, loop
    char* VsC = B + 8192;                       // [64][128B] swizzled, loop
    bf16* KoneS = (bf16*)(B + 16384);           // [64][32] one-hot tile, loop
    bf16* Ps  = (bf16*)(B + 20480);             // [4][16][40] loop (permuted keys)

    const int t = threadIdx.x, wid = t >> 6, lane = t & 63;
    const int lm = lane & 15, quad = lane >> 4;
    const int qbase_l = wid * 16 + quad * 4;
    const int swz = (lm & 7) << 4;

    // phase 0: stage Q tile [64][64] -> LDS (rows clamped for the q tail)
    for (int c = t; c < 512; c += 256) {
        const int row = c >> 3, col = (c & 7) * 8;
        const int qg = min(q0 + row, 1567);
        *(bf16x8*)&Qs[row * 72 + col] =
            *(const bf16x8*)&Qb[((size_t)g * 1568 + qg) * 64 + col];
    }
    __syncthreads();
    const int qrow_l = wid * 16 + lm;
    const bf16x8 qf0 = *(const bf16x8*)&Qs[qrow_l * 72 + quad * 8];
    const bf16x8 qf1 = *(const bf16x8*)&Qs[qrow_l * 72 + 32 + quad * 8];

    // Th-window byte base for THIS LANE's A-fragment row (q-row = qrow_l);
    // per tile the window starts at byte (thb2 - ha*4).
    const int qgl = min(q0 + qrow_l, 1567);
    const int thb2 = (qrow_l * 61 + (qgl / 28 - hqb) + 54) * 4;

    // initial K/V/Kone register prefetch for tile 0 (overlaps prologue MFMAs)
    const int kobase = ((t >> 2) << 5) + ((t & 3) << 3);
    bf16x8 kreg[2], vreg[2], koreg;
#pragma unroll
    for (int i = 0; i < 2; i++) {
        const int idx = (i << 8) + t;
        kreg[i] = *(const bf16x8*)&Kb[((size_t)g * 1568 + (idx >> 3)) * 64 + ((idx & 7) << 3)];
        vreg[i] = *(const bf16x8*)&Vt[((size_t)g * 64 + (idx >> 3)) * 1568 + ((idx & 7) << 3)];
    }
    koreg = *(const bf16x8*)&Kone[kobase];
    __syncthreads();  // all Qs reads done before RPs overwrites

    // phase 1: stage rph rows hqb.. (clamped; only cols<59 consumed), Th MFMA
    for (int c = t; c < 1024; c += 256) {
        const int row = c >> 4, col = (c & 15) * 4;
        const int rg = min(hqb + row, 110);
        *(bf16x4*)&RPs[row * 72 + col] = cvt4(*(const f32x4*)&rph[rg * 64 + col]);
    }
    __syncthreads();
    f32x4 acch[4];
#pragma unroll
    for (int nt = 0; nt < 4; nt++) {
        const bf16x8 b0 = *(const bf16x8*)&RPs[(nt * 16 + lm) * 72 + quad * 8];
        const bf16x8 b1 = *(const bf16x8*)&RPs[(nt * 16 + lm) * 72 + 32 + quad * 8];
        f32x4 a = {};
        a = __builtin_amdgcn_mfma_f32_16x16x32_bf16(qf0, b0, a, 0, 0, 0);
        a = __builtin_amdgcn_mfma_f32_16x16x32_bf16(qf1, b1, a, 0, 0, 0);
        acch[nt] = a;
    }
    __syncthreads();  // all RPh reads done before RPw overwrites

    // phase 2: stage rpw, write Th f32 (*8, col+2 shift), Tw MFMA -> TwF f32
    for (int c = t; c < 1024; c += 256) {
        const int row = c >> 4, col = (c & 15) * 4;
        const int rg = min(row, 54);
        *(bf16x4*)&RPs[row * 72 + col] = cvt4(*(const f32x4*)&rpw[rg * 64 + col]);
    }
#pragma unroll
    for (int nt = 0; nt < 4; nt++) {
        const int c = nt * 16 + lm;
        if (c < 59) {
#pragma unroll
            for (int r = 0; r < 4; r++)
                Th[(qbase_l + r) * 61 + c + 2] = acch[nt][r] * 8.0f;
        }
    }
    __syncthreads();
#pragma unroll
    for (int nt = 0; nt < 4; nt++) {
        const bf16x8 b0 = *(const bf16x8*)&RPs[(nt * 16 + lm) * 72 + quad * 8];
        const bf16x8 b1 = *(const bf16x8*)&RPs[(nt * 16 + lm) * 72 + 32 + quad * 8];
        f32x4 a = {};
        a = __builtin_amdgcn_mfma_f32_16x16x32_bf16(qf0, b0, a, 0, 0, 0);
        a = __builtin_amdgcn_mfma_f32_16x16x32_bf16(qf1, b1, a, 0, 0, 0);
        const int c = nt * 16 + lm;
        if (c < 55) {
#pragma unroll
            for (int r = 0; r < 4; r++)
                TwF[(qbase_l + r) * 58 + c] = a[r] * 8.0f;
        }
    }
    __syncthreads();

    // phase 3: build TwS [64][32] bf16 = per-q-row shifted Tw window.
    // Q'[q][j] = Tw_q[wq+j] for j<28; j 28..31 zeroed (filled per tile with Th).
    {
        const int row = t >> 2, chunk = t & 3;
        const int qg = min(q0 + row, 1567);
        const int wq = qg % 28;
        const float* src = &TwF[row * 58 + wq];
        bf16x8 v;
        if (chunk < 3) {
#pragma unroll
            for (int e = 0; e < 8; e++) v[e] = (bf16)src[chunk * 8 + e];
        } else {
#pragma unroll
            for (int e = 0; e < 4; e++) v[e] = (bf16)src[24 + e];
#pragma unroll
            for (int e = 4; e < 8; e++) v[e] = (bf16)0.0f;
        }
        *(bf16x8*)&TwS[row * 32 + chunk * 8] = v;
    }
    __syncthreads();

    const bf16x8 qt_mine = *(const bf16x8*)&TwS[qrow_l * 32 + quad * 8];

    f32x4 o[4] = {};
    f32x4 lsum = {};
    const f32x4 zero4 = {};
    bf16x8 ones;
#pragma unroll
    for (int i = 0; i < 8; i++) ones[i] = (bf16)1.0f;

    bf16* Pw = &Ps[wid * 640];

    for (int kt = 0; kt < 25; kt++) {
        // Q' quad3 refresh: 4-value Th window (region A; overlaps prev PV)
        const int ha = (kt << 6) / 28;
        const char* tp = ThC + (thb2 - (ha << 2));
        const float w0 = *(const float*)(tp);
        const float w1 = *(const float*)(tp + 4);
        const float w2 = *(const float*)(tp + 8);
        const float w3 = *(const float*)(tp + 12);
        bf16x8 qmod = qt_mine;
        qmod[4] = (bf16)w0; qmod[5] = (bf16)w1;
        qmod[6] = (bf16)w2; qmod[7] = (bf16)w3;
        const bf16x8 qf2 = (quad == 3) ? qmod : qt_mine;

        __syncthreads();                         // prev tile's readers done
        // stage K/V (swizzled) + Kone from regs
#pragma unroll
        for (int i = 0; i < 2; i++) {
            const int idx = (i << 8) + t;
            const int row = idx >> 3;
            const int cb = (((idx & 7) << 4) ^ ((row & 7) << 4));
            *(bf16x8*)(KsC + row * 128 + cb) = kreg[i];
            *(bf16x8*)(VsC + row * 128 + cb) = vreg[i];
        }
        *(bf16x8*)&KoneS[kobase] = koreg;
        // prefetch next tile (addresses clamped in-bounds; garbage is masked)
        {
            const int ktn = min(kt + 1, 24);
            const int kb = ktn << 6;
#pragma unroll
            for (int i = 0; i < 2; i++) {
                const int idx = (i << 8) + t;
                const int krow = min(kb + (idx >> 3), 1567);
                kreg[i] = *(const bf16x8*)&Kb[((size_t)g * 1568 + krow) * 64 + ((idx & 7) << 3)];
                const int vcol = min(kb + ((idx & 7) << 3), 1560);
                vreg[i] = *(const bf16x8*)&Vt[((size_t)g * 64 + (idx >> 3)) * 1568 + vcol];
            }
            koreg = *(const bf16x8*)&Kone[((size_t)ktn << 11) + kobase];
        }
        __syncthreads();

        // S = bias (one-hot MFMA, C=0) + QK^T  (4 key-fragments)
        __builtin_amdgcn_s_setprio(1);
        f32x4 s[4];
#pragma unroll
        for (int f = 0; f < 4; f++) {
            const bf16x8 ko = *(const bf16x8*)&KoneS[(f * 16 + lm) * 32 + quad * 8];
            s[f] = __builtin_amdgcn_mfma_f32_16x16x32_bf16(qf2, ko, zero4, 0, 0, 0);
        }
#pragma unroll
        for (int f = 0; f < 4; f++) {
            const char* rp = KsC + (f * 16 + lm) * 128;
            const int x0 = (quad * 16) ^ swz;
            const bf16x8 ka = *(const bf16x8*)(rp + x0);
            const bf16x8 kb2 = *(const bf16x8*)(rp + (x0 ^ 64));
            s[f] = __builtin_amdgcn_mfma_f32_16x16x32_bf16(qf0, ka, s[f], 0, 0, 0);
            s[f] = __builtin_amdgcn_mfma_f32_16x16x32_bf16(qf1, kb2, s[f], 0, 0, 0);
        }
        __builtin_amdgcn_s_setprio(0);

        if (kt == 24) {                          // keys >= 1568: p == 0
#pragma unroll
            for (int r = 0; r < 4; r++) { s[2][r] = -30000.0f; s[3][r] = -30000.0f; }
        }

        // two 32-key PV halves; P buffer reused (same-wave in-order DS)
#pragma unroll
        for (int h = 0; h < 2; h++) {
#pragma unroll
            for (int r = 0; r < 4; r++) {
                const float p0 = fast_exp2(s[2 * h][r]);
                const float p1 = fast_exp2(s[2 * h + 1][r]);
                bf16x2 pp; pp[0] = (bf16)p0; pp[1] = (bf16)p1;
                *(bf16x2*)&Pw[(quad * 4 + r) * 40 + lm * 2] = pp;
            }
            __asm__ volatile("s_waitcnt lgkmcnt(0)" ::: "memory");
            const bf16x8 pf = *(const bf16x8*)&Pw[lm * 40 + quad * 8];
            lsum = __builtin_amdgcn_mfma_f32_16x16x32_bf16(pf, ones, lsum, 0, 0, 0);
            __builtin_amdgcn_s_setprio(1);
#pragma unroll
            for (int dt = 0; dt < 4; dt++) {
                const bf16x8 vf = *(const bf16x8*)(VsC + (dt * 16 + lm) * 128 +
                                                   (((h << 6) + quad * 16) ^ swz));
                o[dt] = __builtin_amdgcn_mfma_f32_16x16x32_bf16(pf, vf, o[dt], 0, 0, 0);
            }
            __builtin_amdgcn_s_setprio(0);
        }
    }

    // epilogue: lsum already holds per-row softmax denominators (no shuffle)
    if (q0 + wid * 16 < 1568) {
        const int bo = g >> 4, hh = g & 15;
#pragma unroll
        for (int r = 0; r < 4; r++) {
            const float inv = 1.0f / lsum[r];
            const size_t base = ((size_t)bo * 1568 + q0 + qbase_l + r) * 1024 + hh * 64;
#pragma unroll
            for (int dt = 0; dt < 4; dt++)
                AO[base + dt * 16 + lm] = (bf16)(o[dt][r] * inv);
        }
    }
}

// ---------------------------------------------------------------------------
// Kernel 3a: output projection, both operands bf16 (W pre-converted).
__global__ __launch_bounds__(256) void proj_gemm_bf16(
    const bf16* __restrict__ A, const bf16* __restrict__ W,
    const float* __restrict__ bias, float* __restrict__ out) {
    __shared__ bf16 As[128 * 32];
    __shared__ bf16 Bs[128 * 32];
    const int t = threadIdx.x;
    const int wid = t >> 6, lane = t & 63;
    const int m0 = blockIdx.x * 128, n0 = blockIdx.y * 128;
    const int wm = (wid & 1) * 64, wn = (wid >> 1) * 64;
    const int r_i = lane >> 2, c8 = (lane & 3) * 8;
    const int lm = lane & 15, quad = lane >> 4;

    f32x4 acc[4][4] = {};
    for (int k0 = 0; k0 < 1024; k0 += 32) {
        __syncthreads();
        for (int i = 0; i < 2; i++) {
            const int blk = wid * 2 + i;
            async_cp16(A + (size_t)(m0 + blk * 16 + r_i) * 1024 + k0 + c8, As + blk * 512);
            async_cp16(W + (size_t)(n0 + blk * 16 + r_i) * 1024 + k0 + c8, Bs + blk * 512);
        }
        __syncthreads();
        bf16x8 af[4], bfr[4];
        for (int x = 0; x < 4; x++) {
            af[x]  = *(const bf16x8*)&As[(wm + x * 16 + lm) * 32 + quad * 8];
            bfr[x] = *(const bf16x8*)&Bs[(wn + x * 16 + lm) * 32 + quad * 8];
        }
        for (int mt = 0; mt < 4; mt++)
            for (int nt = 0; nt < 4; nt++)
                acc[mt][nt] = __builtin_amdgcn_mfma_f32_16x16x32_bf16(af[mt], bfr[nt], acc[mt][nt], 0, 0, 0);
    }
    for (int nt = 0; nt < 4; nt++) {
        const int n_ = n0 + wn + nt * 16 + lm;
        const float bv = bias[n_];
        for (int mt = 0; mt < 4; mt++)
            for (int r = 0; r < 4; r++) {
                const int m_ = m0 + wm + mt * 16 + quad * 4 + r;
                out[(size_t)m_ * 1024 + n_] = acc[mt][nt][r] + bv;
            }
    }
}

// Kernel 3b: fallback — W fp32, converted at stage time.
__global__ __launch_bounds__(256) void proj_gemm_f32(
    const bf16* __restrict__ A, const float* __restrict__ W,
    const float* __restrict__ bias, float* __restrict__ out) {
    __shared__ bf16 As[128 * 32];
    __shared__ bf16 Bs[128 * 32];
    const int t = threadIdx.x;
    const int wid = t >> 6, lane = t & 63;
    const int m0 = blockIdx.x * 128, n0 = blockIdx.y * 128;
    const int wm = (wid & 1) * 64, wn = (wid >> 1) * 64;
    const int r_i = lane >> 2, c8 = (lane & 3) * 8;
    const int lm = lane & 15, quad = lane >> 4;

    f32x4 acc[4][4] = {};
    for (int k0 = 0; k0 < 1024; k0 += 32) {
        __syncthreads();
        for (int i = 0; i < 2; i++) {
            const int blk = wid * 2 + i;
            async_cp16(A + (size_t)(m0 + blk * 16 + r_i) * 1024 + k0 + c8, As + blk * 512);
        }
        for (int i = 0; i < 4; i++) {
            const int idx = t + i * 256;
            const int row = idx >> 3, c4 = (idx & 7) * 4;
            const f32x4 wv = *(const f32x4*)&W[(size_t)(n0 + row) * 1024 + k0 + c4];
            *(bf16x4*)&Bs[row * 32 + c4] = cvt4(wv);
        }
        __syncthreads();
        bf16x8 af[4], bfr[4];
        for (int x = 0; x < 4; x++) {
            af[x]  = *(const bf16x8*)&As[(wm + x * 16 + lm) * 32 + quad * 8];
            bfr[x] = *(const bf16x8*)&Bs[(wn + x * 16 + lm) * 32 + quad * 8];
        }
        for (int mt = 0; mt < 4; mt++)
            for (int nt = 0; nt < 4; nt++)
                acc[mt][nt] = __builtin_amdgcn_mfma_f32_16x16x32_bf16(af[mt], bfr[nt], acc[mt][nt], 0, 0, 0);
    }
    for (int nt = 0; nt < 4; nt++) {
        const int n_ = n0 + wn + nt * 16 + lm;
        const float bv = bias[n_];
        for (int mt = 0; mt < 4; mt++)
            for (int r = 0; r < 4; r++) {
                const int m_ = m0 + wm + mt * 16 + quad * 4 + r;
                out[(size_t)m_ * 1024 + n_] = acc[mt][nt][r] + bv;
            }
    }
}

// ---------------------------------------------------------------------------
extern "C" void kernel_launch(void* const* d_in, const int* in_sizes, int n_in,
                              void* d_out, int out_size, void* d_ws, size_t ws_size,
                              hipStream_t stream) {
    const float* hs     = (const float*)d_in[0];
    const float* qkv_w  = (const float*)d_in[1];
    const float* qkv_b  = (const float*)d_in[2];
    const float* proj_w = (const float*)d_in[3];
    const float* proj_b = (const float*)d_in[4];
    const float* rph    = (const float*)d_in[5];
    const float* rpw    = (const float*)d_in[6];
    float* out = (float*)d_out;

    const size_t GQ = (size_t)64 * 1568 * 64;  // elems per Q/K/V
    const size_t N_KONE = (size_t)1600 * 32;
    const size_t N_HS = (size_t)6272 * 1024;
    const size_t N_QW = (size_t)3072 * 1024;
    const size_t N_PW = (size_t)1024 * 1024;
    bf16* Qb = (bf16*)d_ws;                    // [g][pix][64] (pre-scaled by C2)
    bf16* Kb = Qb + GQ;                        // [g][pix][64]
    bf16* Vt = Kb + GQ;                        // [g][d][ppix] (permuted keys)
    bf16* AO = Vt + GQ;                        // [6272][1024]
    bf16* Kone = AO + GQ;                      // [1600][32] one-hot
    bf16* hs_bf    = Kone + N_KONE;
    bf16* qkvw_bf  = hs_bf + N_HS;
    bf16* projw_bf = qkvw_bf + N_QW;
    const size_t need = (4 * GQ + N_KONE + N_HS + N_QW + N_PW) * sizeof(bf16);

    if (ws_size >= need) {
        build_kone<<<25, 256, 0, stream>>>(Kone);
        cvt_kernel<<<512, 256, 0, stream>>>(hs, hs_bf, (int)(N_HS / 4));
        cvt_kernel<<<512, 256, 0, stream>>>(qkv_w, qkvw_bf, (int)(N_QW / 4));
        cvt_kernel<<<256, 256, 0, stream>>>(proj_w, projw_bf, (int)(N_PW / 4));
        qkv_gemm_bf16<<<dim3(49, 24), 256, 0, stream>>>(hs_bf, qkvw_bf, qkv_b, Qb, Kb, Vt);
        flash_attn<<<1600, 256, 0, stream>>>(Qb, Kb, Vt, rph, rpw, Kone, AO);
        proj_gemm_bf16<<<dim3(49, 8), 256, 0, stream>>>(AO, projw_bf, proj_b, out);
    } else {
        build_kone<<<25, 256, 0, stream>>>(Kone);
        qkv_gemm_f32<<<dim3(49, 24), 256, 0, stream>>>(hs, qkv_w, qkv_b, Qb, Kb, Vt);
        flash_attn<<<1600, 256, 0, stream>>>(Qb, Kb, Vt, rph, rpw, Kone, AO);
        proj_gemm_f32<<<dim3(49, 8), 256, 0, stream>>>(AO, proj_w, proj_b, out);
    }
}